// Round 3
// baseline (341.623 us; speedup 1.0000x reference)
//
#include <hip/hip_runtime.h>
#include <cfloat>
#include <math.h>

// Brute-force exact-replication KNN (k=10, +self) over 16384 3-D points, two
// instances, then M_i = max_j feats[nbr_rank_j, j-1], out = [feats | M-feats].
//
// Numerics (round 3): replicate an XLA-style self-consistent fp32 pipeline:
//   sq  = fma(z,z, fma(y,y, rn(x*x)))        [mul+reduce fused w/ contraction]
//   dot = fma(z,z', fma(y,y', rn(x*x')))     [gemm fma chain, k ascending]
//   d   = rn(rn(sq_i + sq_j) - rn(2*dot))
// Note sq_i and dot_ii are the IDENTICAL chain -> d_ii == 0.0 exactly; a
// near-twin pair can compute to -1ulp and outrank self — the positional
// rank-0 drop (not "drop self") reproduces the reference in that case too.
// Ties (bitwise-equal d) break by ascending index, matching stable top_k.

#define N_PTS    16384
#define C_FEAT   64
#define KK       11          // K+1 including self
#define TILE     2048        // candidates staged per LDS tile (24 KB)
#define WQ       4           // queries processed concurrently per wave
#define SCANS    2           // sequential scans per wave
#define NWAVES   4
#define NTHREADS (NWAVES * 64)
#define QPB      (NWAVES * WQ * SCANS)   // 32 queries per block

__global__ __launch_bounds__(NTHREADS) void knn_pool_kernel(
    const float* __restrict__ src_f, const float* __restrict__ tgt_f,
    const float* __restrict__ src_c, const float* __restrict__ tgt_c,
    float* __restrict__ out)
{
    const int inst = blockIdx.x & 1;
    const float* __restrict__ feats  = inst ? tgt_f : src_f;
    const float* __restrict__ coords = inst ? tgt_c : src_c;
    float* __restrict__ outb = out + (size_t)inst * (size_t)N_PTS * (2 * C_FEAT);

    const int qblock = (blockIdx.x >> 1) * QPB;
    const int tid   = threadIdx.x;
    const int wave  = tid >> 6;
    const int lane  = tid & 63;
    const int lq    = lane >> 4;      // which query's list this lane belongs to
    const int lrank = lane & 15;      // rank within that list (valid if < KK)
    const bool inlist = (lrank < KK);

    __shared__ float sc[TILE * 3];

    for (int s = 0; s < SCANS; ++s) {
        const int q0 = qblock + wave * (WQ * SCANS) + s * WQ;

        // Query coords + fp32 sq_i, fma chain (k ascending, acc from rn(x*x)).
        float qx[WQ], qy[WQ], qz[WQ], qsq[WQ];
        #pragma unroll
        for (int q = 0; q < WQ; ++q) {
            qx[q] = coords[(q0 + q) * 3 + 0];
            qy[q] = coords[(q0 + q) * 3 + 1];
            qz[q] = coords[(q0 + q) * 3 + 2];
            qsq[q] = __fmaf_rn(qz[q], qz[q],
                     __fmaf_rn(qy[q], qy[q],
                     __fmul_rn(qx[q], qx[q])));
        }

        // Lane-distributed sorted lists: lanes 16q..16q+10 hold (dist,idx),
        // ascending. worst[q] = current 11th-smallest (list tail).
        float ld = FLT_MAX;
        int   li = 0;
        float worst[WQ];
        #pragma unroll
        for (int q = 0; q < WQ; ++q) worst[q] = FLT_MAX;

        for (int t0 = 0; t0 < N_PTS; t0 += TILE) {
            __syncthreads();
            for (int i = tid; i < TILE * 3; i += NTHREADS)
                sc[i] = coords[t0 * 3 + i];
            __syncthreads();

            for (int b = 0; b < TILE; b += 64) {
                const int ci = b + lane;   // candidate slot in tile
                const float cx = sc[ci * 3 + 0];
                const float cy = sc[ci * 3 + 1];
                const float cz = sc[ci * 3 + 2];
                const float csq = __fmaf_rn(cz, cz,
                                  __fmaf_rn(cy, cy,
                                  __fmul_rn(cx, cx)));

                #pragma unroll
                for (int q = 0; q < WQ; ++q) {
                    // dot: fma chain, k = x,y,z ascending (same chain as sq).
                    float dot = __fmul_rn(cx, qx[q]);
                    dot = __fmaf_rn(cy, qy[q], dot);
                    dot = __fmaf_rn(cz, qz[q], dot);
                    // dist = rn(rn(sq_i + sq_j) - rn(2*dot))
                    const float d = __fsub_rn(__fadd_rn(qsq[q], csq),
                                              __fmul_rn(2.0f, dot));

                    unsigned long long m = __ballot(d < worst[q]);
                    while (m) {  // wave-uniform loop, ascending candidate idx
                        const int srcl = __builtin_ctzll(m);
                        m &= m - 1;
                        const float nd = __shfl(d, srcl);
                        if (nd < worst[q]) {   // uniform recheck (worst tightens)
                            const int nj = t0 + b + srcl;
                            // Sorted insert across lanes 16q..16q+10:
                            // entries <= nd stay; entries > nd shift up one;
                            // first shifting lane takes (nd, nj); tail drops.
                            const float pld = __shfl_up(ld, 1);
                            const int   pli = __shfl_up(li, 1);
                            if (inlist && (lq == q) && (ld > nd)) {
                                const bool first = (lrank == 0) || (pld <= nd);
                                ld = first ? nd : pld;
                                li = first ? nj : pli;
                            }
                            worst[q] = __shfl(ld, q * 16 + (KK - 1));
                        }
                    }
                }
            }
        }

        // Rank 0 dropped (self, or a -1ulp near-twin — positional, like ref).
        // Ranks 1..10 map to feature columns 0..9.
        float fv = -FLT_MAX;
        if (inlist && lrank >= 1)
            fv = feats[(size_t)li * C_FEAT + (lrank - 1)];
        #pragma unroll
        for (int off = 1; off < 16; off <<= 1)   // max within 16-lane group
            fv = fmaxf(fv, __shfl_xor(fv, off));

        #pragma unroll
        for (int q = 0; q < WQ; ++q) {
            const float M   = __shfl(fv, q * 16);
            const int   row = q0 + q;
            const float v   = feats[(size_t)row * C_FEAT + lane];
            outb[(size_t)row * (2 * C_FEAT) + lane]          = v;
            outb[(size_t)row * (2 * C_FEAT) + C_FEAT + lane] = M - v;
        }
    }
}

extern "C" void kernel_launch(void* const* d_in, const int* in_sizes, int n_in,
                              void* d_out, int out_size, void* d_ws, size_t ws_size,
                              hipStream_t stream) {
    const float* src_f = (const float*)d_in[0];
    const float* tgt_f = (const float*)d_in[1];
    const float* src_c = (const float*)d_in[2];
    const float* tgt_c = (const float*)d_in[3];
    float* out = (float*)d_out;

    dim3 grid(2 * (N_PTS / QPB));   // 1024 blocks: even=src, odd=tgt
    dim3 block(NTHREADS);           // 256 threads = 4 waves
    hipLaunchKernelGGL(knn_pool_kernel, grid, block, 0, stream,
                       src_f, tgt_f, src_c, tgt_c, out);
}

// Round 4
// 308.683 us; speedup vs baseline: 1.1067x; 1.1067x over previous
//
#include <hip/hip_runtime.h>
#include <cfloat>
#include <math.h>

// Brute-force exact-replication KNN (k=10, +self) over 16384 3-D points, two
// instances, then M_i = max_j feats[nbr_rank_j, j-1], out = [feats | M-feats].
//
// NUMERICS ARE FROZEN (round-3 pass, absmax 0.0): XLA-consistent fp32 chains
//   sq  = fma(z,z, fma(y,y, rn(x*x)))
//   dot = fma(z,z', fma(y,y', rn(x*x')))   [same chain -> d_ii == 0.0 exactly]
//   d   = rn(rn(sq_i + sq_j) - rn(2*dot))
// Stable ascending-index insert == jax top_k tie-break; positional rank-0
// drop; M-v == subtract-then-max by rounding monotonicity. Do not alter.
//
// Round 4 (perf only): occupancy 50%->100%. TILE 2048->1024 (LDS 24->12 KB),
// SCANS 2->1, grid 1024->2048 blocks => 8 blocks/CU * 4 waves = 32 waves/CU,
// hiding the serialized insert-loop shuffle latency (dep chain of 4
// ds_bpermute per insert) and ds_read waits.

#define N_PTS    16384
#define C_FEAT   64
#define KK       11          // K+1 including self
#define TILE     1024        // candidates staged per LDS tile (12 KB)
#define WQ       4           // queries processed concurrently per wave
#define SCANS    1           // sequential scans per wave
#define NWAVES   4
#define NTHREADS (NWAVES * 64)
#define QPB      (NWAVES * WQ * SCANS)   // 16 queries per block

__global__ __launch_bounds__(NTHREADS) void knn_pool_kernel(
    const float* __restrict__ src_f, const float* __restrict__ tgt_f,
    const float* __restrict__ src_c, const float* __restrict__ tgt_c,
    float* __restrict__ out)
{
    const int inst = blockIdx.x & 1;
    const float* __restrict__ feats  = inst ? tgt_f : src_f;
    const float* __restrict__ coords = inst ? tgt_c : src_c;
    float* __restrict__ outb = out + (size_t)inst * (size_t)N_PTS * (2 * C_FEAT);

    const int qblock = (blockIdx.x >> 1) * QPB;
    const int tid   = threadIdx.x;
    const int wave  = tid >> 6;
    const int lane  = tid & 63;
    const int lq    = lane >> 4;      // which query's list this lane belongs to
    const int lrank = lane & 15;      // rank within that list (valid if < KK)
    const bool inlist = (lrank < KK);

    __shared__ float sc[TILE * 3];

    for (int s = 0; s < SCANS; ++s) {
        const int q0 = qblock + wave * (WQ * SCANS) + s * WQ;

        // Query coords + fp32 sq_i, fma chain (k ascending, acc from rn(x*x)).
        float qx[WQ], qy[WQ], qz[WQ], qsq[WQ];
        #pragma unroll
        for (int q = 0; q < WQ; ++q) {
            qx[q] = coords[(q0 + q) * 3 + 0];
            qy[q] = coords[(q0 + q) * 3 + 1];
            qz[q] = coords[(q0 + q) * 3 + 2];
            qsq[q] = __fmaf_rn(qz[q], qz[q],
                     __fmaf_rn(qy[q], qy[q],
                     __fmul_rn(qx[q], qx[q])));
        }

        // Lane-distributed sorted lists: lanes 16q..16q+10 hold (dist,idx),
        // ascending. worst[q] = current 11th-smallest (list tail).
        float ld = FLT_MAX;
        int   li = 0;
        float worst[WQ];
        #pragma unroll
        for (int q = 0; q < WQ; ++q) worst[q] = FLT_MAX;

        for (int t0 = 0; t0 < N_PTS; t0 += TILE) {
            __syncthreads();
            for (int i = tid; i < TILE * 3; i += NTHREADS)
                sc[i] = coords[t0 * 3 + i];
            __syncthreads();

            for (int b = 0; b < TILE; b += 64) {
                const int ci = b + lane;   // candidate slot in tile
                const float cx = sc[ci * 3 + 0];
                const float cy = sc[ci * 3 + 1];
                const float cz = sc[ci * 3 + 2];
                const float csq = __fmaf_rn(cz, cz,
                                  __fmaf_rn(cy, cy,
                                  __fmul_rn(cx, cx)));

                #pragma unroll
                for (int q = 0; q < WQ; ++q) {
                    // dot: fma chain, k = x,y,z ascending (same chain as sq).
                    float dot = __fmul_rn(cx, qx[q]);
                    dot = __fmaf_rn(cy, qy[q], dot);
                    dot = __fmaf_rn(cz, qz[q], dot);
                    // dist = rn(rn(sq_i + sq_j) - rn(2*dot))
                    const float d = __fsub_rn(__fadd_rn(qsq[q], csq),
                                              __fmul_rn(2.0f, dot));

                    unsigned long long m = __ballot(d < worst[q]);
                    while (m) {  // wave-uniform loop, ascending candidate idx
                        const int srcl = __builtin_ctzll(m);
                        m &= m - 1;
                        const float nd = __shfl(d, srcl);
                        if (nd < worst[q]) {   // uniform recheck (worst tightens)
                            const int nj = t0 + b + srcl;
                            // Sorted insert across lanes 16q..16q+10:
                            // entries <= nd stay; entries > nd shift up one;
                            // first shifting lane takes (nd, nj); tail drops.
                            const float pld = __shfl_up(ld, 1);
                            const int   pli = __shfl_up(li, 1);
                            if (inlist && (lq == q) && (ld > nd)) {
                                const bool first = (lrank == 0) || (pld <= nd);
                                ld = first ? nd : pld;
                                li = first ? nj : pli;
                            }
                            worst[q] = __shfl(ld, q * 16 + (KK - 1));
                        }
                    }
                }
            }
        }

        // Rank 0 dropped (self, or a -1ulp near-twin — positional, like ref).
        // Ranks 1..10 map to feature columns 0..9.
        float fv = -FLT_MAX;
        if (inlist && lrank >= 1)
            fv = feats[(size_t)li * C_FEAT + (lrank - 1)];
        #pragma unroll
        for (int off = 1; off < 16; off <<= 1)   // max within 16-lane group
            fv = fmaxf(fv, __shfl_xor(fv, off));

        #pragma unroll
        for (int q = 0; q < WQ; ++q) {
            const float M   = __shfl(fv, q * 16);
            const int   row = q0 + q;
            const float v   = feats[(size_t)row * C_FEAT + lane];
            outb[(size_t)row * (2 * C_FEAT) + lane]          = v;
            outb[(size_t)row * (2 * C_FEAT) + C_FEAT + lane] = M - v;
        }
    }
}

extern "C" void kernel_launch(void* const* d_in, const int* in_sizes, int n_in,
                              void* d_out, int out_size, void* d_ws, size_t ws_size,
                              hipStream_t stream) {
    const float* src_f = (const float*)d_in[0];
    const float* tgt_f = (const float*)d_in[1];
    const float* src_c = (const float*)d_in[2];
    const float* tgt_c = (const float*)d_in[3];
    float* out = (float*)d_out;

    dim3 grid(2 * (N_PTS / QPB));   // 2048 blocks: even=src, odd=tgt
    dim3 block(NTHREADS);           // 256 threads = 4 waves
    hipLaunchKernelGGL(knn_pool_kernel, grid, block, 0, stream,
                       src_f, tgt_f, src_c, tgt_c, out);
}